// Round 8
// baseline (85.895 us; speedup 1.0000x reference)
//
#include <hip/hip_runtime.h>
#include <math.h>

#define H_   16
#define NB_  64
#define D_   1024
#define HID_ 64
#define B_   4
#define T_   2048
#define ROWS (B_*T_)    // 8192
#define HNB  (H_*NB_)   // 1024

__device__ __forceinline__ float gelu_exact(float x) {
    return 0.5f * x * (1.0f + erff(x * 0.7071067811865476f));
}
__device__ __forceinline__ float sigmoidf(float x) {
    return 1.0f / (1.0f + expf(-x));
}

// ---------------- Kernel 1: h = gelu(X @ W1 + b1), register-blocked ---------
// 256 blocks x 32 rows. Thread = (rg = t>>5: 4-row group, cp = t&31: col pair).
// K-chunks of 128. Inner: 4 float4 x-reads + 4 float2 w-reads -> 32 FMAs.
#define FMA8(xa, xb, xc, xd, w) { \
    acc00 = fmaf(xa, (w).x, acc00); acc01 = fmaf(xa, (w).y, acc01); \
    acc10 = fmaf(xb, (w).x, acc10); acc11 = fmaf(xb, (w).y, acc11); \
    acc20 = fmaf(xc, (w).x, acc20); acc21 = fmaf(xc, (w).y, acc21); \
    acc30 = fmaf(xd, (w).x, acc30); acc31 = fmaf(xd, (w).y, acc31); }

__global__ __launch_bounds__(256) void k_gemm1(const float* __restrict__ X,
                                               const float* __restrict__ W1,
                                               const float* __restrict__ b1,
                                               float* __restrict__ hbuf) {
    __shared__ float xs[32][132];   // pad 132 (16B-aligned rows, banks spread)
    __shared__ float ws[128][64];
    const int t  = threadIdx.x;
    const int r0 = blockIdx.x * 32;
    const int rg = t >> 5;     // 0..7
    const int cp = t & 31;     // 0..31
    float acc00=0,acc01=0,acc10=0,acc11=0,acc20=0,acc21=0,acc30=0,acc31=0;

    for (int c = 0; c < 8; ++c) {
        __syncthreads();
        // stage X chunk 32x128 (1024 float4)
        #pragma unroll
        for (int q = 0; q < 4; ++q) {
            int s   = q * 256 + t;
            int row = s >> 5;
            int k4  = s & 31;
            *(float4*)&xs[row][k4 * 4] =
                *(const float4*)&X[(size_t)(r0 + row) * D_ + c * 128 + k4 * 4];
        }
        // stage W1 chunk 128x64 (2048 float4)
        #pragma unroll
        for (int q = 0; q < 8; ++q) {
            int s  = q * 256 + t;
            int k  = s >> 4;
            int j4 = s & 15;
            *(float4*)&ws[k][j4 * 4] =
                *(const float4*)&W1[(size_t)(c * 128 + k) * 64 + j4 * 4];
        }
        __syncthreads();
        #pragma unroll 4
        for (int kq = 0; kq < 32; ++kq) {
            float4 x0 = *(const float4*)&xs[rg * 4 + 0][kq * 4];
            float4 x1 = *(const float4*)&xs[rg * 4 + 1][kq * 4];
            float4 x2 = *(const float4*)&xs[rg * 4 + 2][kq * 4];
            float4 x3 = *(const float4*)&xs[rg * 4 + 3][kq * 4];
            float2 w0 = *(const float2*)&ws[kq * 4 + 0][cp * 2];
            float2 w1 = *(const float2*)&ws[kq * 4 + 1][cp * 2];
            float2 w2 = *(const float2*)&ws[kq * 4 + 2][cp * 2];
            float2 w3 = *(const float2*)&ws[kq * 4 + 3][cp * 2];
            FMA8(x0.x, x1.x, x2.x, x3.x, w0);
            FMA8(x0.y, x1.y, x2.y, x3.y, w1);
            FMA8(x0.z, x1.z, x2.z, x3.z, w2);
            FMA8(x0.w, x1.w, x2.w, x3.w, w3);
        }
    }
    float2 bb = *(const float2*)&b1[cp * 2];
    float2 o;
    o.x = gelu_exact(acc00 + bb.x); o.y = gelu_exact(acc01 + bb.y);
    *(float2*)&hbuf[(size_t)(r0 + rg * 4 + 0) * HID_ + cp * 2] = o;
    o.x = gelu_exact(acc10 + bb.x); o.y = gelu_exact(acc11 + bb.y);
    *(float2*)&hbuf[(size_t)(r0 + rg * 4 + 1) * HID_ + cp * 2] = o;
    o.x = gelu_exact(acc20 + bb.x); o.y = gelu_exact(acc21 + bb.y);
    *(float2*)&hbuf[(size_t)(r0 + rg * 4 + 2) * HID_ + cp * 2] = o;
    o.x = gelu_exact(acc30 + bb.x); o.y = gelu_exact(acc31 + bb.y);
    *(float2*)&hbuf[(size_t)(r0 + rg * 4 + 3) * HID_ + cp * 2] = o;
}

// ---------------- Kernel 2: gates = sigmoid(h @ W2 + b2) ----------------
__global__ __launch_bounds__(256) void k_gemm2(const float* __restrict__ hbuf,
                                               const float* __restrict__ W2,
                                               const float* __restrict__ b2,
                                               float* __restrict__ gates) {
    __shared__ float w2s[64][128];
    __shared__ float hs[16][64];
    const int t  = threadIdx.x;
    const int rb = blockIdx.x >> 3;
    const int kc = blockIdx.x & 7;
    const int r0 = rb * 16;
    const int k0 = kc * 128;

    #pragma unroll
    for (int q = 0; q < 8; ++q) {
        int s  = q * 256 + t;
        int j  = s >> 5;
        int kk = (s & 31) << 2;
        float4 v = *(const float4*)&W2[j * HNB + k0 + kk];
        *(float4*)&w2s[j][kk] = v;
    }
    {
        int rr = t >> 4;
        int jj = (t & 15) << 2;
        *(float4*)&hs[rr][jj] = *(const float4*)&hbuf[(r0 + rr) * HID_ + jj];
    }
    __syncthreads();

    const int kk2 = t & 63;
    const int rq  = t >> 6;
    float a00=0,a01=0,a10=0,a11=0,a20=0,a21=0,a30=0,a31=0;
    #pragma unroll 8
    for (int j = 0; j < 64; ++j) {
        float2 w = *(const float2*)&w2s[j][kk2 * 2];
        float h0 = hs[rq * 4 + 0][j];
        float h1 = hs[rq * 4 + 1][j];
        float h2 = hs[rq * 4 + 2][j];
        float h3 = hs[rq * 4 + 3][j];
        a00 = fmaf(h0, w.x, a00); a01 = fmaf(h0, w.y, a01);
        a10 = fmaf(h1, w.x, a10); a11 = fmaf(h1, w.y, a11);
        a20 = fmaf(h2, w.x, a20); a21 = fmaf(h2, w.y, a21);
        a30 = fmaf(h3, w.x, a30); a31 = fmaf(h3, w.y, a31);
    }
    const int k = k0 + kk2 * 2;
    float2 bb = *(const float2*)&b2[k];
    const int row = r0 + rq * 4;
    float2 o;
    o.x = sigmoidf(a00 + bb.x); o.y = sigmoidf(a01 + bb.y);
    *(float2*)&gates[(row + 0) * HNB + k] = o;
    o.x = sigmoidf(a10 + bb.x); o.y = sigmoidf(a11 + bb.y);
    *(float2*)&gates[(row + 1) * HNB + k] = o;
    o.x = sigmoidf(a20 + bb.x); o.y = sigmoidf(a21 + bb.y);
    *(float2*)&gates[(row + 2) * HNB + k] = o;
    o.x = sigmoidf(a30 + bb.x); o.y = sigmoidf(a31 + bb.y);
    *(float2*)&gates[(row + 3) * HNB + k] = o;
}

// ---------------- Kernel 3: segmented producer-consumer scan v2 ----------
// SEGK=8 segments of 256 steps, warmup 128 steps (4 tiles of TT=32).
// ~50 KiB LDS -> 2 blocks/CU -> all 512 blocks resident in one round.
// Roles: wave0 scan; wave1 loads rows 0-15 (delta+gates, writes paired
// {a, 1-g} float2); wave2 rows 16-31; wave3 storer.
// Paired float2 reads: 1 ds_read_b64/step, max 16 outstanding -> lgkmcnt
// expressible (the 32-outstanding b32 scheme exceeded the 4-bit counter).
#define TT_    32
#define SEGK   8
#define SEGLEN (T_/SEGK)   // 256
#define WARMT  4           // warmup tiles = 128 steps

#define LD8P(A, grp) { \
    _Pragma("unroll") \
    for (int u = 0; u < 8; ++u) A[u] = pa[((grp)*8 + u) * 65]; }

#define CP8P(A, grp) { \
    _Pragma("unroll") \
    for (int u = 0; u < 8; ++u) { \
        float a   = A[u].x; \
        float omg = A[u].y; \
        float aR  = a + R; \
        float pc  = fmaf(omg, a, R); \
        float den = sigma + aR; \
        float s   = sigma + a; \
        float p2  = fmaf(omg, sigma, pc); \
        float rc  = __builtin_amdgcn_rcpf(den); \
        float tt  = s * p2; \
        sigma     = tt * rc; \
        ps[((grp)*8 + u) * 68] = sigma; \
    } }

__global__ __launch_bounds__(256) void k_scan_seg(
        const float* __restrict__ delta,
        const float* __restrict__ gates,
        const float* __restrict__ omega,
        const float* __restrict__ log_Q,
        const float* __restrict__ log_R,
        const float* __restrict__ log_s0,
        float* __restrict__ sig) {
    __shared__ float2 tgp[2][TT_][65];    // {a, 1-g}, ~33 KiB (pad 65)
    __shared__ float  sgl[2][TT_][68];    // sigma out, ~17 KiB (pad 68, 16B-aligned)
    const int tid = threadIdx.x;
    const int blk = blockIdx.x;
    const int bh  = blk >> 3;      // 0..63
    const int seg = blk & 7;
    const int b   = bh >> 4;
    const int h   = bh & 15;
    const size_t base = (size_t)b * T_ * HNB + h * NB_;
    const int wv   = tid >> 6;
    const int lane = tid & 63;

    const int warm   = (seg == 0) ? 0 : WARMT;
    const int ntiles = SEGLEN / TT_ + warm;          // 8 or 12
    const int tstart = seg * SEGLEN - warm * TT_;

    // ---- per-role setup ----
    float R = 0.f, sigma = 0.f;                       // wave0
    float sc0=0,sc1=0,sc2=0,sc3=0;                    // loader waves
    const int col4 = lane & 15;
    const int rr   = lane >> 4;                       // 0..3
    const float* dp = delta + base + col4 * 4;
    const float* gp = gates + base + col4 * 4;

    if (wv == 0) {
        const int hn = h * NB_ + lane;
        R     = expf(log_R[hn]);
        sigma = expf(log_s0[hn]);   // exact for seg 0; warmup guess otherwise
    } else if (wv == 1 || wv == 2) {
        const int hn4 = h * NB_ + col4 * 4;
        float4 om4 = *(const float4*)&omega[hn4];
        float4 lq4 = *(const float4*)&log_Q[hn4];
        sc0 = expf(lq4.x) * om4.x * om4.x;
        sc1 = expf(lq4.y) * om4.y * om4.y;
        sc2 = expf(lq4.z) * om4.z * om4.z;
        sc3 = expf(lq4.w) * om4.w * om4.w;
    }

    for (int p = 0; p <= ntiles + 1; ++p) {
        if (wv == 0) {
            if (p >= 1 && p <= ntiles) {
                const int buf = (p - 1) & 1;
                const float2* pa = &tgp[buf][0][lane];
                float*        ps = &sgl[buf][0][lane];
                float2 A0[8], A1[8];
                LD8P(A0, 0);
                LD8P(A1, 1);
                CP8P(A0, 0); LD8P(A0, 2);
                CP8P(A1, 1); LD8P(A1, 3);
                CP8P(A0, 2);
                CP8P(A1, 3);
            }
        } else if (wv == 1 || wv == 2) {
            if (p < ntiles) {
                const int buf = p & 1;
                const int t0 = tstart + p * TT_;
                const int rbase = (wv - 1) * 16;
                #pragma unroll
                for (int it = 0; it < 4; ++it) {
                    const int row = rbase + it * 4 + rr;
                    float4 d = *(const float4*)&dp[(size_t)(t0 + row) * HNB];
                    float4 g = *(const float4*)&gp[(size_t)(t0 + row) * HNB];
                    tgp[buf][row][col4*4+0] = make_float2((sc0*d.x)*d.x, 1.0f-g.x);
                    tgp[buf][row][col4*4+1] = make_float2((sc1*d.y)*d.y, 1.0f-g.y);
                    tgp[buf][row][col4*4+2] = make_float2((sc2*d.z)*d.z, 1.0f-g.z);
                    tgp[buf][row][col4*4+3] = make_float2((sc3*d.w)*d.w, 1.0f-g.w);
                }
            }
        } else {
            const int tile = p - 2;
            if (tile >= warm && tile < ntiles) {
                const int buf = p & 1;
                const int t0 = tstart + tile * TT_;
                float* op = sig + base + col4 * 4;
                #pragma unroll
                for (int it = 0; it < 8; ++it) {
                    const int row = it * 4 + rr;
                    float4 v = *(const float4*)&sgl[buf][row][col4 * 4];
                    *(float4*)&op[(size_t)(t0 + row) * HNB] = v;
                }
            }
        }
        __syncthreads();
    }
}

extern "C" void kernel_launch(void* const* d_in, const int* in_sizes, int n_in,
                              void* d_out, int out_size, void* d_ws, size_t ws_size,
                              hipStream_t stream) {
    const float* delta   = (const float*)d_in[0];
    const float* content = (const float*)d_in[1];
    const float* omega   = (const float*)d_in[2];
    const float* log_Q   = (const float*)d_in[3];
    const float* log_R   = (const float*)d_in[4];
    const float* log_s0  = (const float*)d_in[5];
    const float* W1      = (const float*)d_in[6];
    const float* b1      = (const float*)d_in[7];
    const float* W2      = (const float*)d_in[8];
    const float* b2      = (const float*)d_in[9];

    float* sig_out   = (float*)d_out;                    // 8388608 floats
    float* gates_out = sig_out + (size_t)ROWS * HNB;     // next 8388608

    const size_t n_h = (size_t)ROWS * HID_;              // 524288
    // h scratch: workspace if available, else sigma region of d_out (fully
    // overwritten by the scan afterwards, stream-ordered).
    float* hbuf = (ws_size >= n_h * sizeof(float)) ? (float*)d_ws : sig_out;

    k_gemm1<<<ROWS / 32, 256, 0, stream>>>(content, W1, b1, hbuf);
    k_gemm2<<<(ROWS / 16) * 8, 256, 0, stream>>>(hbuf, W2, b2, gates_out);
    k_scan_seg<<<B_ * H_ * SEGK, 256, 0, stream>>>(delta, gates_out, omega,
                                                   log_Q, log_R, log_s0, sig_out);
}

// Round 9
// 78.968 us; speedup vs baseline: 1.0877x; 1.0877x over previous
//
#include <hip/hip_runtime.h>
#include <math.h>

#define H_   16
#define NB_  64
#define D_   1024
#define HID_ 64
#define B_   4
#define T_   2048
#define ROWS (B_*T_)    // 8192
#define HNB  (H_*NB_)   // 1024

typedef short v8s __attribute__((ext_vector_type(8)));
typedef float v4f __attribute__((ext_vector_type(4)));

__device__ __forceinline__ float gelu_exact(float x) {
    return 0.5f * x * (1.0f + erff(x * 0.7071067811865476f));
}
__device__ __forceinline__ float sigmoidf(float x) {
    return 1.0f / (1.0f + expf(-x));
}
__device__ __forceinline__ ushort f2bf(float x) {   // RNE float->bf16 bits
    union { float f; unsigned u; } v; v.f = x;
    unsigned r = v.u + 0x7fffu + ((v.u >> 16) & 1u);
    return (ushort)(r >> 16);
}

// ---------------- Kernel 0: W1 (1024x64 f32) -> W1T (64x1024 bf16) ----------
__global__ __launch_bounds__(256) void k_prep_w1t(const float* __restrict__ W1,
                                                  ushort* __restrict__ w1t) {
    __shared__ float ls[64][65];
    const int t  = threadIdx.x;
    const int k0 = blockIdx.x * 64;
    #pragma unroll
    for (int q = 0; q < 4; ++q) {
        int idx = q * 256 + t;
        int r   = idx >> 4;
        int c4  = idx & 15;
        *(float4*)&ls[r][c4 * 4] = *(const float4*)&W1[(size_t)(k0 + r) * 64 + c4 * 4];
    }
    __syncthreads();
    const int col = t >> 2, kq = t & 3;
    ushort out[16];
    #pragma unroll
    for (int e = 0; e < 16; ++e) out[e] = f2bf(ls[kq * 16 + e][col]);
    *(uint4*)&w1t[(size_t)col * 1024 + k0 + kq * 16]     = *(uint4*)&out[0];
    *(uint4*)&w1t[(size_t)col * 1024 + k0 + kq * 16 + 8] = *(uint4*)&out[8];
}

// ---------------- Kernel 1: h = gelu(X @ W1 + b1) via bf16 MFMA -------------
// 128 blocks x 64 rows, 4 waves. Wave w owns M-rows w*16..+15, all 64 N-cols
// (4 C-frags). K-chunks of 128 single-buffered in LDS (A and W1T, bf16,
// XOR-swizzled k ^= (row&7)<<3 against the stride-256B bank conflict).
__global__ __launch_bounds__(256) void k_gemm1_mfma(const float* __restrict__ X,
                                                    const ushort* __restrict__ w1t,
                                                    const float* __restrict__ b1,
                                                    float* __restrict__ hbuf) {
    __shared__ ushort Al[64 * 128];
    __shared__ ushort Bl[64 * 128];
    const int t    = threadIdx.x;
    const int r0   = blockIdx.x * 64;
    const int w    = t >> 6;
    const int lane = t & 63;
    const int lo   = lane & 15;
    const int hi   = lane >> 4;
    const int srow = t >> 2;      // staging row (A) / col (B), 0..63
    const int skb  = t & 3;       // staging k-block (32 k each)

    v4f acc[4];
    #pragma unroll
    for (int nt = 0; nt < 4; ++nt) acc[nt] = (v4f){0.f, 0.f, 0.f, 0.f};

    for (int c = 0; c < 8; ++c) {
        // -- read staging data (global) --
        float xv[32];
        const float* xp = &X[(size_t)(r0 + srow) * D_ + c * 128 + skb * 32];
        #pragma unroll
        for (int i = 0; i < 8; ++i) *(float4*)&xv[i * 4] = *(const float4*)&xp[i * 4];
        ushort wv[32];
        const ushort* wp = &w1t[(size_t)srow * 1024 + c * 128 + skb * 32];
        #pragma unroll
        for (int i = 0; i < 4; ++i) *(uint4*)&wv[i * 8] = *(const uint4*)&wp[i * 8];

        __syncthreads();   // previous chunk's compute done
        #pragma unroll
        for (int g = 0; g < 4; ++g) {
            const int k   = skb * 32 + g * 8;
            const int swk = k ^ ((srow & 7) << 3);
            union { ushort u[8]; v8s v; } pa;
            #pragma unroll
            for (int e = 0; e < 8; ++e) pa.u[e] = f2bf(xv[g * 8 + e]);
            *(v8s*)&Al[srow * 128 + swk] = pa.v;
            *(v8s*)&Bl[srow * 128 + swk] = *(v8s*)&wv[g * 8];
        }
        __syncthreads();   // chunk staged

        const int rowa = w * 16 + lo;
        #pragma unroll
        for (int kk = 0; kk < 4; ++kk) {
            const int k = kk * 32 + hi * 8;
            v8s af = *(v8s*)&Al[rowa * 128 + (k ^ ((rowa & 7) << 3))];
            const int swb = k ^ ((lo & 7) << 3);   // (nt*16+lo)&7 == lo&7
            v8s b0 = *(v8s*)&Bl[(0 * 16 + lo) * 128 + swb];
            v8s b1f = *(v8s*)&Bl[(1 * 16 + lo) * 128 + swb];
            v8s b2 = *(v8s*)&Bl[(2 * 16 + lo) * 128 + swb];
            v8s b3 = *(v8s*)&Bl[(3 * 16 + lo) * 128 + swb];
            acc[0] = __builtin_amdgcn_mfma_f32_16x16x32_bf16(af, b0,  acc[0], 0, 0, 0);
            acc[1] = __builtin_amdgcn_mfma_f32_16x16x32_bf16(af, b1f, acc[1], 0, 0, 0);
            acc[2] = __builtin_amdgcn_mfma_f32_16x16x32_bf16(af, b2,  acc[2], 0, 0, 0);
            acc[3] = __builtin_amdgcn_mfma_f32_16x16x32_bf16(af, b3,  acc[3], 0, 0, 0);
        }
    }
    // epilogue: C layout col = lane&15, row = (lane>>4)*4 + j  [m89-verified]
    #pragma unroll
    for (int nt = 0; nt < 4; ++nt) {
        const float bb = b1[nt * 16 + lo];
        #pragma unroll
        for (int j = 0; j < 4; ++j) {
            const int row = r0 + w * 16 + hi * 4 + j;
            hbuf[(size_t)row * HID_ + nt * 16 + lo] = gelu_exact(acc[nt][j] + bb);
        }
    }
}

// ---------------- Kernel 2: gates = sigmoid(h @ W2 + b2) ----------------
__global__ __launch_bounds__(256) void k_gemm2(const float* __restrict__ hbuf,
                                               const float* __restrict__ W2,
                                               const float* __restrict__ b2,
                                               float* __restrict__ gates) {
    __shared__ float w2s[64][128];
    __shared__ float hs[16][64];
    const int t  = threadIdx.x;
    const int rb = blockIdx.x >> 3;
    const int kc = blockIdx.x & 7;
    const int r0 = rb * 16;
    const int k0 = kc * 128;

    #pragma unroll
    for (int q = 0; q < 8; ++q) {
        int s  = q * 256 + t;
        int j  = s >> 5;
        int kk = (s & 31) << 2;
        float4 v = *(const float4*)&W2[j * HNB + k0 + kk];
        *(float4*)&w2s[j][kk] = v;
    }
    {
        int rr = t >> 4;
        int jj = (t & 15) << 2;
        *(float4*)&hs[rr][jj] = *(const float4*)&hbuf[(r0 + rr) * HID_ + jj];
    }
    __syncthreads();

    const int kk2 = t & 63;
    const int rq  = t >> 6;
    float a00=0,a01=0,a10=0,a11=0,a20=0,a21=0,a30=0,a31=0;
    #pragma unroll 8
    for (int j = 0; j < 64; ++j) {
        float2 w = *(const float2*)&w2s[j][kk2 * 2];
        float h0 = hs[rq * 4 + 0][j];
        float h1 = hs[rq * 4 + 1][j];
        float h2 = hs[rq * 4 + 2][j];
        float h3 = hs[rq * 4 + 3][j];
        a00 = fmaf(h0, w.x, a00); a01 = fmaf(h0, w.y, a01);
        a10 = fmaf(h1, w.x, a10); a11 = fmaf(h1, w.y, a11);
        a20 = fmaf(h2, w.x, a20); a21 = fmaf(h2, w.y, a21);
        a30 = fmaf(h3, w.x, a30); a31 = fmaf(h3, w.y, a31);
    }
    const int k = k0 + kk2 * 2;
    float2 bb = *(const float2*)&b2[k];
    const int row = r0 + rq * 4;
    float2 o;
    o.x = sigmoidf(a00 + bb.x); o.y = sigmoidf(a01 + bb.y);
    *(float2*)&gates[(row + 0) * HNB + k] = o;
    o.x = sigmoidf(a10 + bb.x); o.y = sigmoidf(a11 + bb.y);
    *(float2*)&gates[(row + 1) * HNB + k] = o;
    o.x = sigmoidf(a20 + bb.x); o.y = sigmoidf(a21 + bb.y);
    *(float2*)&gates[(row + 2) * HNB + k] = o;
    o.x = sigmoidf(a30 + bb.x); o.y = sigmoidf(a31 + bb.y);
    *(float2*)&gates[(row + 3) * HNB + k] = o;
}

// ---------------- Kernel 3: segmented producer-consumer scan ----------
// SEGK=8 segments of 256 steps, warmup 128 steps (4 tiles of TT=32).
#define TT_    32
#define SEGK   8
#define SEGLEN (T_/SEGK)   // 256
#define WARMT  4           // warmup tiles = 128 steps

#define LD8P(A, grp) { \
    _Pragma("unroll") \
    for (int u = 0; u < 8; ++u) A[u] = pa[((grp)*8 + u) * 65]; }

#define CP8P(A, grp) { \
    _Pragma("unroll") \
    for (int u = 0; u < 8; ++u) { \
        float a   = A[u].x; \
        float omg = A[u].y; \
        float aR  = a + R; \
        float pc  = fmaf(omg, a, R); \
        float den = sigma + aR; \
        float s   = sigma + a; \
        float p2  = fmaf(omg, sigma, pc); \
        float rc  = __builtin_amdgcn_rcpf(den); \
        float tt  = s * p2; \
        sigma     = tt * rc; \
        ps[((grp)*8 + u) * 68] = sigma; \
    } }

__global__ __launch_bounds__(256) void k_scan_seg(
        const float* __restrict__ delta,
        const float* __restrict__ gates,
        const float* __restrict__ omega,
        const float* __restrict__ log_Q,
        const float* __restrict__ log_R,
        const float* __restrict__ log_s0,
        float* __restrict__ sig) {
    __shared__ float2 tgp[2][TT_][65];
    __shared__ float  sgl[2][TT_][68];
    const int tid = threadIdx.x;
    const int blk = blockIdx.x;
    const int bh  = blk >> 3;
    const int seg = blk & 7;
    const int b   = bh >> 4;
    const int h   = bh & 15;
    const size_t base = (size_t)b * T_ * HNB + h * NB_;
    const int wv   = tid >> 6;
    const int lane = tid & 63;

    const int warm   = (seg == 0) ? 0 : WARMT;
    const int ntiles = SEGLEN / TT_ + warm;
    const int tstart = seg * SEGLEN - warm * TT_;

    float R = 0.f, sigma = 0.f;
    float sc0=0,sc1=0,sc2=0,sc3=0;
    const int col4 = lane & 15;
    const int rr   = lane >> 4;
    const float* dp = delta + base + col4 * 4;
    const float* gp = gates + base + col4 * 4;

    if (wv == 0) {
        const int hn = h * NB_ + lane;
        R     = expf(log_R[hn]);
        sigma = expf(log_s0[hn]);
    } else if (wv == 1 || wv == 2) {
        const int hn4 = h * NB_ + col4 * 4;
        float4 om4 = *(const float4*)&omega[hn4];
        float4 lq4 = *(const float4*)&log_Q[hn4];
        sc0 = expf(lq4.x) * om4.x * om4.x;
        sc1 = expf(lq4.y) * om4.y * om4.y;
        sc2 = expf(lq4.z) * om4.z * om4.z;
        sc3 = expf(lq4.w) * om4.w * om4.w;
    }

    for (int p = 0; p <= ntiles + 1; ++p) {
        if (wv == 0) {
            if (p >= 1 && p <= ntiles) {
                const int buf = (p - 1) & 1;
                const float2* pa = &tgp[buf][0][lane];
                float*        ps = &sgl[buf][0][lane];
                float2 A0[8], A1[8];
                LD8P(A0, 0);
                LD8P(A1, 1);
                CP8P(A0, 0); LD8P(A0, 2);
                CP8P(A1, 1); LD8P(A1, 3);
                CP8P(A0, 2);
                CP8P(A1, 3);
            }
        } else if (wv == 1 || wv == 2) {
            if (p < ntiles) {
                const int buf = p & 1;
                const int t0 = tstart + p * TT_;
                const int rbase = (wv - 1) * 16;
                #pragma unroll
                for (int it = 0; it < 4; ++it) {
                    const int row = rbase + it * 4 + rr;
                    float4 d = *(const float4*)&dp[(size_t)(t0 + row) * HNB];
                    float4 g = *(const float4*)&gp[(size_t)(t0 + row) * HNB];
                    tgp[buf][row][col4*4+0] = make_float2((sc0*d.x)*d.x, 1.0f-g.x);
                    tgp[buf][row][col4*4+1] = make_float2((sc1*d.y)*d.y, 1.0f-g.y);
                    tgp[buf][row][col4*4+2] = make_float2((sc2*d.z)*d.z, 1.0f-g.z);
                    tgp[buf][row][col4*4+3] = make_float2((sc3*d.w)*d.w, 1.0f-g.w);
                }
            }
        } else {
            const int tile = p - 2;
            if (tile >= warm && tile < ntiles) {
                const int buf = p & 1;
                const int t0 = tstart + tile * TT_;
                float* op = sig + base + col4 * 4;
                #pragma unroll
                for (int it = 0; it < 8; ++it) {
                    const int row = it * 4 + rr;
                    float4 v = *(const float4*)&sgl[buf][row][col4 * 4];
                    *(float4*)&op[(size_t)(t0 + row) * HNB] = v;
                }
            }
        }
        __syncthreads();
    }
}

extern "C" void kernel_launch(void* const* d_in, const int* in_sizes, int n_in,
                              void* d_out, int out_size, void* d_ws, size_t ws_size,
                              hipStream_t stream) {
    const float* delta   = (const float*)d_in[0];
    const float* content = (const float*)d_in[1];
    const float* omega   = (const float*)d_in[2];
    const float* log_Q   = (const float*)d_in[3];
    const float* log_R   = (const float*)d_in[4];
    const float* log_s0  = (const float*)d_in[5];
    const float* W1      = (const float*)d_in[6];
    const float* b1      = (const float*)d_in[7];
    const float* W2      = (const float*)d_in[8];
    const float* b2      = (const float*)d_in[9];

    float* sig_out   = (float*)d_out;                    // 8388608 floats
    float* gates_out = sig_out + (size_t)ROWS * HNB;     // next 8388608

    const size_t n_h    = (size_t)ROWS * HID_;           // 524288 floats (2 MB)
    const size_t n_w1t  = (size_t)HID_ * D_;             // 65536 ushorts (128 KB)
    const size_t need   = n_h * sizeof(float) + n_w1t * sizeof(ushort);

    float*  hbuf;
    ushort* w1t;
    if (ws_size >= need) {
        hbuf = (float*)d_ws;
        w1t  = (ushort*)(hbuf + n_h);
    } else {
        // sigma region of d_out as scratch (fully overwritten by scan after)
        hbuf = sig_out;
        w1t  = (ushort*)(sig_out + n_h);
    }

    k_prep_w1t<<<D_ / 64, 256, 0, stream>>>(W1, w1t);
    k_gemm1_mfma<<<ROWS / 64, 256, 0, stream>>>(content, w1t, b1, hbuf);
    k_gemm2<<<(ROWS / 16) * 8, 256, 0, stream>>>(hbuf, W2, b2, gates_out);
    k_scan_seg<<<B_ * H_ * SEGK, 256, 0, stream>>>(delta, gates_out, omega,
                                                   log_Q, log_R, log_s0, sig_out);
}

// Round 10
// 59.540 us; speedup vs baseline: 1.4426x; 1.3263x over previous
//
#include <hip/hip_runtime.h>
#include <math.h>

#define H_   16
#define NB_  64
#define D_   1024
#define HID_ 64
#define B_   4
#define T_   2048
#define ROWS (B_*T_)    // 8192
#define HNB  (H_*NB_)   // 1024

typedef short v8s __attribute__((ext_vector_type(8)));
typedef float v4f __attribute__((ext_vector_type(4)));

__device__ __forceinline__ float gelu_exact(float x) {
    return 0.5f * x * (1.0f + erff(x * 0.7071067811865476f));
}
__device__ __forceinline__ float sigmoidf(float x) {
    return 1.0f / (1.0f + expf(-x));
}
__device__ __forceinline__ ushort f2bf(float x) {   // RNE float->bf16 bits
    union { float f; unsigned u; } v; v.f = x;
    unsigned r = v.u + 0x7fffu + ((v.u >> 16) & 1u);
    return (ushort)(r >> 16);
}

// ------- Kernel 0: prep. blk<16: W1(1024x64 f32)->w1t(64x1024 bf16);
//                   blk>=16: W2(64x1024 f32)->w2t(1024x64 bf16). -------
__global__ __launch_bounds__(256) void k_prep(const float* __restrict__ W1,
                                              const float* __restrict__ W2,
                                              ushort* __restrict__ w1t,
                                              ushort* __restrict__ w2t) {
    __shared__ float ls[64][65];
    const int t   = threadIdx.x;
    const int blk = blockIdx.x;
    if (blk < 16) {
        const int k0 = blk * 64;
        #pragma unroll
        for (int q = 0; q < 4; ++q) {
            int idx = q * 256 + t;
            int r = idx >> 4, c4 = idx & 15;
            *(float4*)&ls[r][c4 * 4] =
                *(const float4*)&W1[(size_t)(k0 + r) * 64 + c4 * 4];
        }
        __syncthreads();
        const int col = t >> 2, kq = t & 3;
        ushort out[16];
        #pragma unroll
        for (int e = 0; e < 16; ++e) out[e] = f2bf(ls[kq * 16 + e][col]);
        *(uint4*)&w1t[(size_t)col * 1024 + k0 + kq * 16]     = *(uint4*)&out[0];
        *(uint4*)&w1t[(size_t)col * 1024 + k0 + kq * 16 + 8] = *(uint4*)&out[8];
    } else {
        const int n0 = (blk - 16) * 64;
        #pragma unroll
        for (int q = 0; q < 4; ++q) {
            int idx = q * 256 + t;
            int r = idx >> 4, c4 = idx & 15;    // r = k (0..63)
            *(float4*)&ls[r][c4 * 4] =
                *(const float4*)&W2[(size_t)r * HNB + n0 + c4 * 4];
        }
        __syncthreads();
        const int n = t >> 2, kq = t & 3;
        ushort out[16];
        #pragma unroll
        for (int e = 0; e < 16; ++e) out[e] = f2bf(ls[kq * 16 + e][n]);
        *(uint4*)&w2t[(size_t)(n0 + n) * 64 + kq * 16]     = *(uint4*)&out[0];
        *(uint4*)&w2t[(size_t)(n0 + n) * 64 + kq * 16 + 8] = *(uint4*)&out[8];
    }
}

// ------- Kernel 1: h(bf16) = gelu(X @ W1 + b1), MFMA, BM=32, grid 256 -------
// 4 waves: wave w -> M-frag mt=w&1 (rows mt*16..+15), N-half nh=w>>1 (2 frags).
__global__ __launch_bounds__(256) void k_gemm1_mfma(const float* __restrict__ X,
                                                    const ushort* __restrict__ w1t,
                                                    const float* __restrict__ b1,
                                                    ushort* __restrict__ hbuf) {
    __shared__ ushort Al[32 * 128];
    __shared__ ushort Bl[64 * 128];
    const int t    = threadIdx.x;
    const int r0   = blockIdx.x * 32;
    const int w    = t >> 6;
    const int lane = t & 63;
    const int lo   = lane & 15;
    const int hi   = lane >> 4;
    const int mt   = w & 1;
    const int nh   = w >> 1;
    const int arow = t >> 3, aseg = t & 7;   // A stage: 32 rows x 8 segs(16k)
    const int brow = t >> 2, bseg = t & 3;   // B stage: 64 rows x 4 segs(32k)

    v4f acc0 = {0.f,0.f,0.f,0.f}, acc1 = {0.f,0.f,0.f,0.f};

    for (int c = 0; c < 8; ++c) {
        float xv[16];
        const float* xp = &X[(size_t)(r0 + arow) * D_ + c * 128 + aseg * 16];
        #pragma unroll
        for (int i = 0; i < 4; ++i) *(float4*)&xv[i*4] = *(const float4*)&xp[i*4];
        ushort wv[32];
        const ushort* wp = &w1t[(size_t)brow * 1024 + c * 128 + bseg * 32];
        #pragma unroll
        for (int i = 0; i < 4; ++i) *(uint4*)&wv[i*8] = *(const uint4*)&wp[i*8];

        __syncthreads();   // previous chunk's compute done
        #pragma unroll
        for (int j8 = 0; j8 < 2; ++j8) {
            const int k = aseg * 16 + j8 * 8;
            union { ushort u[8]; v8s v; } pa;
            #pragma unroll
            for (int e = 0; e < 8; ++e) pa.u[e] = f2bf(xv[j8 * 8 + e]);
            *(v8s*)&Al[arow * 128 + (k ^ ((arow & 7) << 3))] = pa.v;
        }
        #pragma unroll
        for (int j8 = 0; j8 < 4; ++j8) {
            const int k = bseg * 32 + j8 * 8;
            *(v8s*)&Bl[brow * 128 + (k ^ ((brow & 7) << 3))] = *(v8s*)&wv[j8 * 8];
        }
        __syncthreads();   // chunk staged

        const int rowa = mt * 16 + lo;
        #pragma unroll
        for (int kk = 0; kk < 4; ++kk) {
            const int k   = kk * 32 + hi * 8;
            const int sw  = k ^ ((lo & 7) << 3);
            v8s af  = *(v8s*)&Al[rowa * 128 + sw];
            v8s b0  = *(v8s*)&Bl[(nh * 32 + lo) * 128 + sw];
            v8s b1v = *(v8s*)&Bl[(nh * 32 + 16 + lo) * 128 + sw];
            acc0 = __builtin_amdgcn_mfma_f32_16x16x32_bf16(af, b0,  acc0, 0, 0, 0);
            acc1 = __builtin_amdgcn_mfma_f32_16x16x32_bf16(af, b1v, acc1, 0, 0, 0);
        }
    }
    #pragma unroll
    for (int nt = 0; nt < 2; ++nt) {
        v4f a = nt ? acc1 : acc0;
        const int col = nh * 32 + nt * 16 + lo;
        const float bb = b1[col];
        #pragma unroll
        for (int j = 0; j < 4; ++j) {
            const int row = r0 + mt * 16 + hi * 4 + j;
            hbuf[(size_t)row * HID_ + col] = f2bf(gelu_exact(a[j] + bb));
        }
    }
}

// ------- Kernel 2: gates = sigmoid(h @ W2 + b2), MFMA, tile 64x256 -------
// grid 512 (128 M-blocks x 4 N-blocks). K=64 = 2 MFMA k-steps, staged once.
__global__ __launch_bounds__(256) void k_gemm2_mfma(const ushort* __restrict__ hbuf,
                                                    const ushort* __restrict__ w2t,
                                                    const float* __restrict__ b2,
                                                    float* __restrict__ gates) {
    __shared__ ushort Ah[64 * 64];     // 8 KiB
    __shared__ ushort Bh[256 * 64];    // 32 KiB
    const int t    = threadIdx.x;
    const int r0   = (blockIdx.x >> 2) * 64;
    const int n0   = (blockIdx.x & 3) * 256;
    const int w    = t >> 6;
    const int lane = t & 63;
    const int lo   = lane & 15;
    const int hi   = lane >> 4;

    // stage A: 64 rows x 4 segs(16k) = 256 slots, 1 per thread
    {
        const int row = t >> 2, seg = t & 3;
        uint4 v0 = *(const uint4*)&hbuf[(size_t)(r0 + row) * 64 + seg * 16];
        uint4 v1 = *(const uint4*)&hbuf[(size_t)(r0 + row) * 64 + seg * 16 + 8];
        const int sw = (row & 7) << 3;
        *(uint4*)&Ah[row * 64 + ((seg * 16) ^ sw)]     = v0;
        *(uint4*)&Ah[row * 64 + ((seg * 16 + 8) ^ sw)] = v1;
    }
    // stage B: 256 n-rows x 4 segs = 1024 slots, 4 per thread
    #pragma unroll
    for (int q = 0; q < 4; ++q) {
        const int pi  = q * 256 + t;
        const int n   = pi >> 2, seg = pi & 3;
        uint4 v0 = *(const uint4*)&w2t[(size_t)(n0 + n) * 64 + seg * 16];
        uint4 v1 = *(const uint4*)&w2t[(size_t)(n0 + n) * 64 + seg * 16 + 8];
        const int sw = (n & 7) << 3;
        *(uint4*)&Bh[n * 64 + ((seg * 16) ^ sw)]     = v0;
        *(uint4*)&Bh[n * 64 + ((seg * 16 + 8) ^ sw)] = v1;
    }
    __syncthreads();

    v4f acc[4][4];
    #pragma unroll
    for (int mt = 0; mt < 4; ++mt)
        #pragma unroll
        for (int nt = 0; nt < 4; ++nt) acc[mt][nt] = (v4f){0.f,0.f,0.f,0.f};

    #pragma unroll
    for (int kc = 0; kc < 2; ++kc) {
        const int k  = kc * 32 + hi * 8;
        const int sw = k ^ ((lo & 7) << 3);
        v8s af[4];
        #pragma unroll
        for (int mt = 0; mt < 4; ++mt)
            af[mt] = *(v8s*)&Ah[(mt * 16 + lo) * 64 + sw];
        #pragma unroll
        for (int nt = 0; nt < 4; ++nt) {
            v8s bf = *(v8s*)&Bh[(w * 64 + nt * 16 + lo) * 64 + sw];
            #pragma unroll
            for (int mt = 0; mt < 4; ++mt)
                acc[mt][nt] = __builtin_amdgcn_mfma_f32_16x16x32_bf16(af[mt], bf, acc[mt][nt], 0, 0, 0);
        }
    }

    #pragma unroll
    for (int nt = 0; nt < 4; ++nt) {
        const int col = n0 + w * 64 + nt * 16 + lo;
        const float bb = b2[col];
        #pragma unroll
        for (int mt = 0; mt < 4; ++mt) {
            #pragma unroll
            for (int j = 0; j < 4; ++j) {
                const int row = r0 + mt * 16 + hi * 4 + j;
                gates[(size_t)row * HNB + col] = sigmoidf(acc[mt][nt][j] + bb);
            }
        }
    }
}

// ---------------- Kernel 3: segmented producer-consumer scan ----------------
// SEGK=4 segments of 512 steps, warmup 128 steps (2 tiles of TT=64). R6 config.
#define TT_   64
#define SEGK  4
#define SEGLEN (T_/SEGK)   // 512
#define WARMT  2

#define LD8(A, G, grp) { \
    _Pragma("unroll") \
    for (int u = 0; u < 8; ++u) { \
        A[u] = pa[((grp)*8 + u) * 128]; \
        G[u] = pa[((grp)*8 + u) * 128 + 64]; \
    } }

#define CP8(A, G, grp) { \
    _Pragma("unroll") \
    for (int u = 0; u < 8; ++u) { \
        float a   = A[u]; \
        float omg = G[u]; \
        float aR  = a + R; \
        float pc  = fmaf(omg, a, R); \
        float den = sigma + aR; \
        float s   = sigma + a; \
        float p   = fmaf(omg, sigma, pc); \
        float rc  = __builtin_amdgcn_rcpf(den); \
        float tt  = s * p; \
        sigma     = tt * rc; \
        ps[((grp)*8 + u) * 64] = sigma; \
    } }

__global__ __launch_bounds__(256) void k_scan_seg(
        const float* __restrict__ delta,
        const float* __restrict__ gates,
        const float* __restrict__ omega,
        const float* __restrict__ log_Q,
        const float* __restrict__ log_R,
        const float* __restrict__ log_s0,
        float* __restrict__ sig) {
    __shared__ float tg_lds[2][TT_][2][64];   // a-plane / (1-g)-plane, 64 KiB
    __shared__ float sg_lds[2][TT_][64];      // 32 KiB
    const int tid = threadIdx.x;
    const int blk = blockIdx.x;
    const int bh  = blk >> 2;
    const int seg = blk & 3;
    const int b   = bh >> 4;
    const int h   = bh & 15;
    const size_t base = (size_t)b * T_ * HNB + h * NB_;
    const int wv   = tid >> 6;
    const int lane = tid & 63;

    const int warm   = (seg == 0) ? 0 : WARMT;
    const int ntiles = SEGLEN / TT_ + warm;          // 8 or 10
    const int tstart = seg * SEGLEN - warm * TT_;

    float R = 0.f, sigma = 0.f;
    float sc0=0,sc1=0,sc2=0,sc3=0;
    const int col4 = lane & 15;
    const int rg   = lane >> 4;
    const float* dp = delta + base + col4 * 4;
    const float* gp = gates + base + col4 * 4;

    if (wv == 0) {
        const int hn = h * NB_ + lane;
        R     = expf(log_R[hn]);
        sigma = expf(log_s0[hn]);
    } else if (wv == 1) {
        const int hn4 = h * NB_ + col4 * 4;
        float4 om4 = *(const float4*)&omega[hn4];
        float4 lq4 = *(const float4*)&log_Q[hn4];
        sc0 = expf(lq4.x) * om4.x * om4.x;
        sc1 = expf(lq4.y) * om4.y * om4.y;
        sc2 = expf(lq4.z) * om4.z * om4.z;
        sc3 = expf(lq4.w) * om4.w * om4.w;
    }

    for (int p = 0; p <= ntiles + 1; ++p) {
        if (wv == 0) {
            if (p >= 1 && p <= ntiles) {
                const int buf = (p - 1) & 1;
                const float* pa = &tg_lds[buf][0][0][lane];
                float*       ps = &sg_lds[buf][0][lane];
                float a0[8], g0[8], a1[8], g1[8];
                LD8(a0, g0, 0);
                LD8(a1, g1, 1);
                CP8(a0, g0, 0); LD8(a0, g0, 2);
                CP8(a1, g1, 1); LD8(a1, g1, 3);
                CP8(a0, g0, 2); LD8(a0, g0, 4);
                CP8(a1, g1, 3); LD8(a1, g1, 5);
                CP8(a0, g0, 4); LD8(a0, g0, 6);
                CP8(a1, g1, 5); LD8(a1, g1, 7);
                CP8(a0, g0, 6);
                CP8(a1, g1, 7);
            }
        } else if (wv == 1) {
            if (p < ntiles) {
                const int buf = p & 1;
                const int t0 = tstart + p * TT_;
                #pragma unroll
                for (int it = 0; it < 16; ++it) {
                    const int row = it * 4 + rg;
                    float4 d = *(const float4*)&dp[(size_t)(t0 + row) * HNB];
                    float4 a;
                    a.x = (sc0 * d.x) * d.x;
                    a.y = (sc1 * d.y) * d.y;
                    a.z = (sc2 * d.z) * d.z;
                    a.w = (sc3 * d.w) * d.w;
                    *(float4*)&tg_lds[buf][row][0][col4 * 4] = a;
                }
            }
        } else if (wv == 2) {
            if (p < ntiles) {
                const int buf = p & 1;
                const int t0 = tstart + p * TT_;
                #pragma unroll
                for (int it = 0; it < 16; ++it) {
                    const int row = it * 4 + rg;
                    float4 g = *(const float4*)&gp[(size_t)(t0 + row) * HNB];
                    float4 o;
                    o.x = 1.0f - g.x; o.y = 1.0f - g.y;
                    o.z = 1.0f - g.z; o.w = 1.0f - g.w;
                    *(float4*)&tg_lds[buf][row][1][col4 * 4] = o;
                }
            }
        } else {
            const int tile = p - 2;
            if (tile >= warm && tile < ntiles) {
                const int buf = p & 1;
                const int t0 = tstart + tile * TT_;
                float* op = sig + base + col4 * 4;
                #pragma unroll
                for (int it = 0; it < 16; ++it) {
                    const int row = it * 4 + rg;
                    float4 v = *(const float4*)&sg_lds[buf][row][col4 * 4];
                    *(float4*)&op[(size_t)(t0 + row) * HNB] = v;
                }
            }
        }
        __syncthreads();
    }
}

extern "C" void kernel_launch(void* const* d_in, const int* in_sizes, int n_in,
                              void* d_out, int out_size, void* d_ws, size_t ws_size,
                              hipStream_t stream) {
    const float* delta   = (const float*)d_in[0];
    const float* content = (const float*)d_in[1];
    const float* omega   = (const float*)d_in[2];
    const float* log_Q   = (const float*)d_in[3];
    const float* log_R   = (const float*)d_in[4];
    const float* log_s0  = (const float*)d_in[5];
    const float* W1      = (const float*)d_in[6];
    const float* b1      = (const float*)d_in[7];
    const float* W2      = (const float*)d_in[8];
    const float* b2      = (const float*)d_in[9];

    float* sig_out   = (float*)d_out;                    // 8388608 floats
    float* gates_out = sig_out + (size_t)ROWS * HNB;     // next 8388608

    const size_t n_h   = (size_t)ROWS * HID_;            // 524288 bf16
    const size_t n_w1t = (size_t)HID_ * D_;              // 65536 bf16
    const size_t n_w2t = (size_t)HNB * HID_;             // 65536 bf16
    const size_t need  = (n_h + n_w1t + n_w2t) * sizeof(ushort);

    ushort *hbuf, *w1t, *w2t;
    if (ws_size >= need) {
        hbuf = (ushort*)d_ws;
    } else {
        hbuf = (ushort*)sig_out;   // scratch in sigma region (overwritten by scan)
    }
    w1t = hbuf + n_h;
    w2t = w1t + n_w1t;

    k_prep<<<32, 256, 0, stream>>>(W1, W2, w1t, w2t);
    k_gemm1_mfma<<<ROWS / 32, 256, 0, stream>>>(content, w1t, b1, hbuf);
    k_gemm2_mfma<<<(ROWS / 64) * 4, 256, 0, stream>>>(hbuf, w2t, b2, gates_out);
    k_scan_seg<<<B_ * H_ * SEGK, 256, 0, stream>>>(delta, gates_out, omega,
                                                   log_Q, log_R, log_s0, sig_out);
}